// Round 6
// baseline (244.437 us; speedup 1.0000x reference)
//
#include <hip/hip_runtime.h>
#include <cstdint>
#include <cstddef>

typedef unsigned int u32;
typedef unsigned long long u64;

#define NB 8192
#define BIMG 2
#define WPR (NB / 64)   // 128 u64 words per mask row

// ---------------- workspace layout (bytes) ----------------
#define WS_KCOUNT 0
#define WS_KEYS   256
#define WS_BOXES  (WS_KEYS + BIMG * NB * 8)          // 131328
#define WS_PROB   (WS_BOXES + BIMG * NB * 16)        // 393472
#define WS_SBOXES (WS_PROB + BIMG * NB * 4)          // 459008
#define WS_SPROB  (WS_SBOXES + BIMG * NB * 16)       // 721152
#define WS_REMV   (WS_SPROB + BIMG * NB * 4)         // 786688
#define WS_MASK   (WS_REMV + BIMG * WPR * 8 + 256)   // 788992 (pad)
#define WS_ROWNZ  (WS_MASK + (size_t)BIMG * NB * WPR * 8)
#define WS_NEEDED (WS_ROWNZ + (size_t)BIMG * NB)     // ~17.6 MB

// ---------------------------------------------------------------------------
// Kernel 1: sigmoid + box decode + sort-key build (NO atomics)
// ---------------------------------------------------------------------------
__global__ void decode_kernel(const float* __restrict__ offsets,
                              const float* __restrict__ labels,
                              const float* __restrict__ anchors,
                              u64* __restrict__ keys,
                              float4* __restrict__ boxes,
                              float* __restrict__ prob) {
  int idx = blockIdx.x * blockDim.x + threadIdx.x;
  if (idx >= BIMG * NB) return;
  int n = idx & (NB - 1);

  float logit = labels[idx];
  float p = 1.0f / (1.0f + expf(-logit));
  bool valid = p > 0.5f;

  const float4 an = ((const float4*)anchors)[n];   // x1,y1,x2,y2
  float acx = (an.x + an.z) / 2.0f;
  float acy = (an.y + an.w) / 2.0f;
  float aw = an.z - an.x;
  float ah = an.w - an.y;

  const float4 of = ((const float4*)offsets)[idx]; // gcx,gcy,gw,gh
  float cx = of.x * aw / 10.0f + acx;
  float cy = of.y * ah / 10.0f + acy;
  float w = expf(of.z / 5.0f) * aw;
  float h = expf(of.w / 5.0f) * ah;

  float4 bx;
  bx.x = cx - w / 2.0f;
  bx.y = cy - h / 2.0f;
  bx.z = cx + w / 2.0f;
  bx.w = cy + h / 2.0f;
  boxes[idx] = bx;
  prob[idx] = p;

  u32 e = valid ? (__float_as_uint(p) ^ 0x80000000u) : 0u;
  keys[idx] = ((u64)e << 32) | (u32)(~(u32)n);
}

// ---------------------------------------------------------------------------
// Kernel 2: per-image bitonic sort (desc) + valid count + fused sorted gather
// (IX swizzle from round 4 reverted: measured neutral-to-harmful)
// ---------------------------------------------------------------------------
__global__ __launch_bounds__(1024) void sort_kernel(u64* __restrict__ keys,
                                                    const float4* __restrict__ boxes,
                                                    const float* __restrict__ prob,
                                                    float4* __restrict__ sboxes,
                                                    float* __restrict__ sprob,
                                                    u32* __restrict__ kcount) {
  __shared__ u64 s[NB];                 // 64 KB
  __shared__ u32 scnt;
  const int b = blockIdx.x;
  u64* kb = keys + (size_t)b * NB;
  if (threadIdx.x == 0) scnt = 0;
  u32 lc = 0;
  for (int i = threadIdx.x; i < NB; i += 1024) {
    u64 k = kb[i];
    s[i] = k;
    lc += ((u32)(k >> 32) != 0u) ? 1u : 0u;
  }
  // wave reduction of local valid count
  for (int off = 32; off > 0; off >>= 1) lc += __shfl_down(lc, off, 64);
  __syncthreads();                       // scnt init + s[] loaded
  if ((threadIdx.x & 63) == 0) atomicAdd(&scnt, lc);   // 16 LDS atomics
  __syncthreads();
  if (threadIdx.x == 0) kcount[b] = scnt;

  for (int k = 2; k <= NB; k <<= 1) {
    for (int j = k >> 1; j > 0; j >>= 1) {
      for (int p = threadIdx.x; p < NB / 2; p += 1024) {
        int i = ((p & ~(j - 1)) << 1) | (p & (j - 1));
        int ixj = i | j;
        u64 a = s[i];
        u64 c = s[ixj];
        bool desc = (i & k) == 0;
        if ((a < c) == desc) { s[i] = c; s[ixj] = a; }
      }
      __syncthreads();
    }
  }

  // write back keys + fused gather into sorted order
  const float4* bx = boxes + (size_t)b * NB;
  const float* pb = prob + (size_t)b * NB;
  for (int i = threadIdx.x; i < NB; i += 1024) {
    u64 k = s[i];
    kb[i] = k;
    u32 oi = (u32)(~k);                 // original anchor index
    sboxes[(size_t)b * NB + i] = bx[oi];
    sprob[(size_t)b * NB + i]  = pb[oi];
  }
}

// ---------------------------------------------------------------------------
// Kernel 4: overlap bitmask build + per-row nonzero flag.
// mask[b][i][w] bit l = (j=64w+l) > i && j < K && IoU(i,j) > 0.5
// ---------------------------------------------------------------------------
__global__ __launch_bounds__(256) void mask_kernel(const float4* __restrict__ sboxes,
                                                   const u32* __restrict__ kcount,
                                                   u64* __restrict__ mask,
                                                   unsigned char* __restrict__ rownz) {
  const int i = blockIdx.x;       // sorted row
  const int b = blockIdx.y;
  const int K = (int)kcount[b];
  if (i >= K) return;
  const int wave = threadIdx.x >> 6;
  const int lane = threadIdx.x & 63;
  __shared__ u32 anyf[4];
  const float4* sb = sboxes + (size_t)b * NB;
  const float4 bi = sb[i];
  const float area_i = (bi.z - bi.x) * (bi.w - bi.y);
  u64* mrow = mask + ((size_t)b * NB + i) * WPR;
  bool any = false;
  for (int pass = 0; pass < WPR / 4; ++pass) {
    int w = pass * 4 + wave;
    u64 word = 0;
    if ((w + 1) * 64 > i && w * 64 < K) {   // uniform per wave
      int j = w * 64 + lane;
      float4 bj = sb[j];
      float lx = fmaxf(bi.x, bj.x);
      float ly = fmaxf(bi.y, bj.y);
      float rx = fminf(bi.z, bj.z);
      float ry = fminf(bi.w, bj.w);
      float iw = fmaxf(rx - lx, 0.0f);
      float ih = fmaxf(ry - ly, 0.0f);
      float inter = iw * ih;
      float area_j = (bj.z - bj.x) * (bj.w - bj.y);
      float iou = inter / (area_i + area_j - inter);
      bool pred = (j > i) && (j < K) && (iou > 0.5f);
      word = __ballot(pred);
      any = any || (word != 0ull);
    }
    if (lane == 0) mrow[w] = word;
  }
  if (lane == 0) anyf[wave] = any ? 1u : 0u;
  __syncthreads();
  if (threadIdx.x == 0) {
    u32 a = anyf[0] | anyf[1] | anyf[2] | anyf[3];
    rownz[(size_t)b * NB + i] = (unsigned char)(a ? 1 : 0);
  }
}

// ---------------------------------------------------------------------------
// Kernel 5: chunked greedy scan, 1 wave per image, software-pipelined so that
// NO load is consumed in the stage it was issued:
//  - dw/nz/specA gathers prefetched 2 stages ahead (static addresses)
//  - specA = word (c) of chunk (c-1) rows, masked by ku_{c-1} at use,
//    shfl-reduced -> next chunk's remv word without a round trip
//  - full-row loads of kept rows issued at stage c, ORed at stage c+2
//    (two ping-ponged 32-row register sets); >32 overflow handled sync (rare)
//  - resolve loop pruned with nzd &= ~rc
// ---------------------------------------------------------------------------
__device__ inline u64 rdl64(u64 v, int lane) {
  u32 lo = (u32)__builtin_amdgcn_readlane((int)(u32)v, lane);
  u32 hi = (u32)__builtin_amdgcn_readlane((int)(u32)(v >> 32), lane);
  return ((u64)hi << 32) | lo;
}

__device__ inline u64 shflxor64(u64 v, int off) {
  u32 lo = (u32)v, hi = (u32)(v >> 32);
  lo = (u32)__shfl_xor((int)lo, off, 64);
  hi = (u32)__shfl_xor((int)hi, off, 64);
  return ((u64)hi << 32) | lo;
}

__global__ __launch_bounds__(64) void scan_kernel(const u64* __restrict__ mask,
                                                  const unsigned char* __restrict__ rownz,
                                                  const u32* __restrict__ kcount,
                                                  u64* __restrict__ remv) {
  const int b = blockIdx.x;
  const int lid = threadIdx.x;
  const int K = (int)kcount[b];
  const u64* mb = mask + (size_t)b * NB * WPR;
  const unsigned char* nzb = rownz + (size_t)b * NB;

  // init remv: bits >= K are suppressed from the start
  u64 r0, r1;
  {
    int lo0 = (2 * lid) * 64, lo1 = (2 * lid + 1) * 64;
    r0 = (lo0 + 64 <= K) ? 0ull : ((lo0 >= K) ? ~0ull : ((~0ull) << (K - lo0)));
    r1 = (lo1 + 64 <= K) ? 0ull : ((lo1 >= K) ? ~0ull : ((~0ull) << (K - lo1)));
  }

  const int NC = min(WPR, (K + 63) >> 6);

  // deferred batch register sets (static indexing only)
  ulonglong2 v0[32], v1[32];
  bool va0 = false, vg0 = false, va1 = false, vg1b = false;

  // 2-deep pipeline registers
  u64 dw = 0, dw1 = 0, dw2 = 0;
  unsigned char nz = 0, nzn1 = 0, nzn2 = 0;
  u64 spA = 0, spA1 = 0, spA2 = 0;
  u64 kuPrev = 0;
  bool haveKu = false;

  if (NC > 0) { dw = mb[(size_t)lid * WPR]; nz = nzb[lid]; }
  if (NC > 1) {
    dw1 = mb[(size_t)(64 + lid) * WPR + 1];
    nzn1 = nzb[64 + lid];
    spA1 = mb[(size_t)lid * WPR + 1];     // word 1 of chunk-0 rows
  }

  for (int c = 0; c < NC; ++c) {
    // --- A: prefetch stage c+2 (all addresses static) ---
    if (c + 2 < NC) {
      dw2  = mb[(size_t)((c + 2) * 64 + lid) * WPR + (c + 2)];
      nzn2 = nzb[(c + 2) * 64 + lid];
      spA2 = mb[(size_t)((c + 1) * 64 + lid) * WPR + (c + 2)];  // word c+2 of chunk c+1 rows
    } else { dw2 = 0; nzn2 = 0; spA2 = 0; }

    // --- B: OR deferred batch from stage c-2 (same-parity set) ---
    if ((c & 1) == 0) {
      if (va0) {
#pragma unroll
        for (int q = 0; q < 16; ++q) { r0 |= v0[q].x; r1 |= v0[q].y; }
        if (vg0) {
#pragma unroll
          for (int q = 16; q < 32; ++q) { r0 |= v0[q].x; r1 |= v0[q].y; }
        }
        va0 = false; vg0 = false;
      }
    } else {
      if (va1) {
#pragma unroll
        for (int q = 0; q < 16; ++q) { r0 |= v1[q].x; r1 |= v1[q].y; }
        if (vg1b) {
#pragma unroll
          for (int q = 16; q < 32; ++q) { r0 |= v1[q].x; r1 |= v1[q].y; }
        }
        va1 = false; vg1b = false;
      }
    }

    // --- C: build current suppressed word, resolve diagonal ---
    const int owner = c >> 1;
    u64 rc = rdl64((c & 1) ? r1 : r0, owner);
    if (haveKu) {
      u64 m = ((kuPrev >> lid) & 1ull) ? spA : 0ull;   // word c of chunk c-1 kept rows
#pragma unroll
      for (int off = 32; off > 0; off >>= 1) m |= shflxor64(m, off);
      rc |= m;
    }
    u64 nzd = __ballot(dw != 0ull) & ~rc;
    while (nzd) {
      int l = __builtin_ctzll(nzd);
      rc |= rdl64(dw, l);
      nzd &= ~(1ull << l) & ~rc;          // prune suppressed candidates
    }
    if (lid == owner) { if (c & 1) r1 = rc; else r0 = rc; }

    // --- D: kept-with-bits rows -> fill deferred batch (parity c&1) ---
    u64 nzword = __ballot(nz != 0);
    u64 ku = (~rc) & nzword;
    kuPrev = ku;
    haveKu = true;
    if (ku) {
      int last = __builtin_ctzll(ku);
      u64 kk = ku;
      if ((c & 1) == 0) {
#pragma unroll
        for (int q = 0; q < 16; ++q) {
          int l_ = kk ? __builtin_ctzll(kk) : last;
          if (kk) kk &= kk - 1;
          v0[q] = ((const ulonglong2*)(mb + (size_t)(c * 64 + l_) * WPR))[lid];
        }
        va0 = true;
        vg0 = (kk != 0ull);
        if (vg0) {
#pragma unroll
          for (int q = 16; q < 32; ++q) {
            int l_ = kk ? __builtin_ctzll(kk) : last;
            if (kk) kk &= kk - 1;
            v0[q] = ((const ulonglong2*)(mb + (size_t)(c * 64 + l_) * WPR))[lid];
          }
        }
      } else {
#pragma unroll
        for (int q = 0; q < 16; ++q) {
          int l_ = kk ? __builtin_ctzll(kk) : last;
          if (kk) kk &= kk - 1;
          v1[q] = ((const ulonglong2*)(mb + (size_t)(c * 64 + l_) * WPR))[lid];
        }
        va1 = true;
        vg1b = (kk != 0ull);
        if (vg1b) {
#pragma unroll
          for (int q = 16; q < 32; ++q) {
            int l_ = kk ? __builtin_ctzll(kk) : last;
            if (kk) kk &= kk - 1;
            v1[q] = ((const ulonglong2*)(mb + (size_t)(c * 64 + l_) * WPR))[lid];
          }
        }
      }
      // overflow (>32 kept rows in one chunk): synchronous, rare
      while (kk) {
        ulonglong2 t[16];
#pragma unroll
        for (int q = 0; q < 16; ++q) {
          int l_ = kk ? __builtin_ctzll(kk) : last;
          if (kk) kk &= kk - 1;
          t[q] = ((const ulonglong2*)(mb + (size_t)(c * 64 + l_) * WPR))[lid];
        }
#pragma unroll
        for (int q = 0; q < 16; ++q) { r0 |= t[q].x; r1 |= t[q].y; }
      }
    }

    // --- rotate pipeline ---
    dw = dw1;  dw1 = dw2;
    nz = nzn1; nzn1 = nzn2;
    spA = spA1; spA1 = spA2;
  }

  // epilogue: OR batches still in flight
  if (va0) {
#pragma unroll
    for (int q = 0; q < 16; ++q) { r0 |= v0[q].x; r1 |= v0[q].y; }
    if (vg0) {
#pragma unroll
      for (int q = 16; q < 32; ++q) { r0 |= v0[q].x; r1 |= v0[q].y; }
    }
  }
  if (va1) {
#pragma unroll
    for (int q = 0; q < 16; ++q) { r0 |= v1[q].x; r1 |= v1[q].y; }
    if (vg1b) {
#pragma unroll
      for (int q = 16; q < 32; ++q) { r0 |= v1[q].x; r1 |= v1[q].y; }
    }
  }

  remv[(size_t)b * WPR + 2 * lid]     = r0;
  remv[(size_t)b * WPR + 2 * lid + 1] = r1;
}

// ---------------------------------------------------------------------------
// Kernel 6: output write
// ---------------------------------------------------------------------------
__global__ void output_kernel(const float4* __restrict__ sboxes,
                              const float* __restrict__ sprob,
                              const u64* __restrict__ remv,
                              const u32* __restrict__ kcount,
                              float* __restrict__ out) {
  int idx = blockIdx.x * blockDim.x + threadIdx.x;
  if (idx >= BIMG * NB) return;
  int b = idx / NB;
  int p = idx - b * NB;
  int K = (int)kcount[b];
  u64 w = remv[(size_t)b * WPR + (p >> 6)];
  bool kp = (p < K) && !((w >> (p & 63)) & 1ull);
  float4 bv = sboxes[idx];
  if (!kp) { bv.x = 0.0f; bv.y = 0.0f; bv.z = 0.0f; bv.w = 0.0f; }
  ((float4*)out)[idx] = bv;
  out[(size_t)BIMG * NB * 4 + idx] = kp ? sprob[idx] : 0.0f;
  out[(size_t)BIMG * NB * 5 + idx] = kp ? 1.0f : 0.0f;
}

// ---------------------------------------------------------------------------
// Fallback NMS kernel (used only if workspace is too small)
// ---------------------------------------------------------------------------
__global__ __launch_bounds__(1024) void nms_kernel(const u64* __restrict__ keys,
                                                   const float4* __restrict__ boxes,
                                                   const float* __restrict__ prob,
                                                   const u32* __restrict__ kcount,
                                                   float* __restrict__ out) {
  __shared__ float4 sb[NB];
  __shared__ unsigned char flag[NB];
  const int b = blockIdx.x;
  const int t = threadIdx.x;
  const u64* kb = keys + (size_t)b * NB;
  const float4* bx = boxes + (size_t)b * NB;
  const int K = (int)kcount[b];

  for (int p = t; p < NB; p += 1024) {
    u32 idx = (u32)(~kb[p]);
    sb[p] = bx[idx];
    flag[p] = (p < K) ? (unsigned char)0 : (unsigned char)1;
  }
  __syncthreads();

  for (int i = 0; i < K; ++i) {
    if (flag[i]) continue;
    float4 bi = sb[i];
    float area_i = (bi.z - bi.x) * (bi.w - bi.y);
    for (int j = i + 1 + t; j < K; j += 1024) {
      float4 bj = sb[j];
      float lx = fmaxf(bi.x, bj.x);
      float ly = fmaxf(bi.y, bj.y);
      float rx = fminf(bi.z, bj.z);
      float ry = fminf(bi.w, bj.w);
      float iw = fmaxf(rx - lx, 0.0f);
      float ih = fmaxf(ry - ly, 0.0f);
      float inter = iw * ih;
      float area_j = (bj.z - bj.x) * (bj.w - bj.y);
      float iou = inter / (area_i + area_j - inter);
      if (iou > 0.5f) flag[j] = (unsigned char)1;
    }
    __syncthreads();
  }

  float4* oboxes = (float4*)(out) + (size_t)b * NB;
  float* oscores = out + (size_t)BIMG * NB * 4 + (size_t)b * NB;
  float* okeep   = out + (size_t)BIMG * NB * 5 + (size_t)b * NB;
  const float* pb = prob + (size_t)b * NB;
  for (int p = t; p < NB; p += 1024) {
    bool kp = (p < K) && (flag[p] == 0);
    float4 bv = sb[p];
    if (!kp) { bv.x = 0.0f; bv.y = 0.0f; bv.z = 0.0f; bv.w = 0.0f; }
    oboxes[p] = bv;
    u32 idx = (u32)(~kb[p]);
    oscores[p] = kp ? pb[idx] : 0.0f;
    okeep[p] = kp ? 1.0f : 0.0f;
  }
}

// ---------------------------------------------------------------------------
extern "C" void kernel_launch(void* const* d_in, const int* in_sizes, int n_in,
                              void* d_out, int out_size, void* d_ws, size_t ws_size,
                              hipStream_t stream) {
  const float* offsets = (const float*)d_in[0];   // [B,N,4] f32
  const float* labels  = (const float*)d_in[1];   // [B,N,1] f32
  const float* anchors = (const float*)d_in[2];   // [N,4]   f32
  float* out = (float*)d_out;

  char* ws = (char*)d_ws;
  u32*    kcount = (u32*)(ws + WS_KCOUNT);
  u64*    keys   = (u64*)(ws + WS_KEYS);
  float4* boxes  = (float4*)(ws + WS_BOXES);
  float*  prob   = (float*)(ws + WS_PROB);
  float4* sboxes = (float4*)(ws + WS_SBOXES);
  float*  sprob  = (float*)(ws + WS_SPROB);

  int total = BIMG * NB;
  decode_kernel<<<(total + 255) / 256, 256, 0, stream>>>(
      offsets, labels, anchors, keys, boxes, prob);

  sort_kernel<<<BIMG, 1024, 0, stream>>>(keys, boxes, prob, sboxes, sprob, kcount);

  if (ws_size >= WS_NEEDED) {
    u64*    remv   = (u64*)(ws + WS_REMV);
    u64*    mask   = (u64*)(ws + WS_MASK);
    unsigned char* rownz = (unsigned char*)(ws + WS_ROWNZ);

    mask_kernel<<<dim3(NB, BIMG), 256, 0, stream>>>(sboxes, kcount, mask, rownz);

    scan_kernel<<<BIMG, 64, 0, stream>>>(mask, rownz, kcount, remv);

    output_kernel<<<(total + 255) / 256, 256, 0, stream>>>(
        sboxes, sprob, remv, kcount, out);
  } else {
    nms_kernel<<<BIMG, 1024, 0, stream>>>(keys, boxes, prob, kcount, out);
  }
}

// Round 7
// 220.890 us; speedup vs baseline: 1.1066x; 1.1066x over previous
//
#include <hip/hip_runtime.h>
#include <cstdint>
#include <cstddef>

typedef unsigned int u32;
typedef unsigned long long u64;

#define NB 8192
#define BIMG 2
#define WPR (NB / 64)   // 128 u64 words per mask row

// ---------------- workspace layout (bytes) ----------------
#define WS_KCOUNT 0
#define WS_KEYS   256
#define WS_BOXES  (WS_KEYS + BIMG * NB * 8)          // 131328
#define WS_PROB   (WS_BOXES + BIMG * NB * 16)        // 393472
#define WS_SBOXES (WS_PROB + BIMG * NB * 4)          // 459008
#define WS_SPROB  (WS_SBOXES + BIMG * NB * 16)       // 721152
#define WS_REMV   (WS_SPROB + BIMG * NB * 4)         // 786688
#define WS_MASK   (WS_REMV + BIMG * WPR * 8 + 256)   // 788992 (pad)
#define WS_ROWNZ  (WS_MASK + (size_t)BIMG * NB * WPR * 8)
#define WS_NEEDED (WS_ROWNZ + (size_t)BIMG * NB)     // ~17.6 MB

// ---------------------------------------------------------------------------
// Kernel 1: sigmoid + box decode + sort-key build (NO atomics)
// ---------------------------------------------------------------------------
__global__ void decode_kernel(const float* __restrict__ offsets,
                              const float* __restrict__ labels,
                              const float* __restrict__ anchors,
                              u64* __restrict__ keys,
                              float4* __restrict__ boxes,
                              float* __restrict__ prob) {
  int idx = blockIdx.x * blockDim.x + threadIdx.x;
  if (idx >= BIMG * NB) return;
  int n = idx & (NB - 1);

  float logit = labels[idx];
  float p = 1.0f / (1.0f + expf(-logit));
  bool valid = p > 0.5f;

  const float4 an = ((const float4*)anchors)[n];   // x1,y1,x2,y2
  float acx = (an.x + an.z) / 2.0f;
  float acy = (an.y + an.w) / 2.0f;
  float aw = an.z - an.x;
  float ah = an.w - an.y;

  const float4 of = ((const float4*)offsets)[idx]; // gcx,gcy,gw,gh
  float cx = of.x * aw / 10.0f + acx;
  float cy = of.y * ah / 10.0f + acy;
  float w = expf(of.z / 5.0f) * aw;
  float h = expf(of.w / 5.0f) * ah;

  float4 bx;
  bx.x = cx - w / 2.0f;
  bx.y = cy - h / 2.0f;
  bx.z = cx + w / 2.0f;
  bx.w = cy + h / 2.0f;
  boxes[idx] = bx;
  prob[idx] = p;

  u32 e = valid ? (__float_as_uint(p) ^ 0x80000000u) : 0u;
  keys[idx] = ((u64)e << 32) | (u32)(~(u32)n);
}

// ---------------------------------------------------------------------------
// Kernel 2: per-image bitonic sort (desc) + valid count + fused sorted gather
// ---------------------------------------------------------------------------
__global__ __launch_bounds__(1024) void sort_kernel(u64* __restrict__ keys,
                                                    const float4* __restrict__ boxes,
                                                    const float* __restrict__ prob,
                                                    float4* __restrict__ sboxes,
                                                    float* __restrict__ sprob,
                                                    u32* __restrict__ kcount) {
  __shared__ u64 s[NB];                 // 64 KB
  __shared__ u32 scnt;
  const int b = blockIdx.x;
  u64* kb = keys + (size_t)b * NB;
  if (threadIdx.x == 0) scnt = 0;
  u32 lc = 0;
  for (int i = threadIdx.x; i < NB; i += 1024) {
    u64 k = kb[i];
    s[i] = k;
    lc += ((u32)(k >> 32) != 0u) ? 1u : 0u;
  }
  // wave reduction of local valid count
  for (int off = 32; off > 0; off >>= 1) lc += __shfl_down(lc, off, 64);
  __syncthreads();                       // scnt init + s[] loaded
  if ((threadIdx.x & 63) == 0) atomicAdd(&scnt, lc);   // 16 LDS atomics
  __syncthreads();
  if (threadIdx.x == 0) kcount[b] = scnt;

  for (int k = 2; k <= NB; k <<= 1) {
    for (int j = k >> 1; j > 0; j >>= 1) {
      for (int p = threadIdx.x; p < NB / 2; p += 1024) {
        int i = ((p & ~(j - 1)) << 1) | (p & (j - 1));
        int ixj = i | j;
        u64 a = s[i];
        u64 c = s[ixj];
        bool desc = (i & k) == 0;
        if ((a < c) == desc) { s[i] = c; s[ixj] = a; }
      }
      __syncthreads();
    }
  }

  // write back keys + fused gather into sorted order
  const float4* bx = boxes + (size_t)b * NB;
  const float* pb = prob + (size_t)b * NB;
  for (int i = threadIdx.x; i < NB; i += 1024) {
    u64 k = s[i];
    kb[i] = k;
    u32 oi = (u32)(~k);                 // original anchor index
    sboxes[(size_t)b * NB + i] = bx[oi];
    sprob[(size_t)b * NB + i]  = pb[oi];
  }
}

// ---------------------------------------------------------------------------
// Kernel 4: overlap bitmask build + per-row nonzero flag.
// mask[b][i][w] bit l = (j=64w+l) > i && j < K && IoU(i,j) > 0.5
// ---------------------------------------------------------------------------
__global__ __launch_bounds__(256) void mask_kernel(const float4* __restrict__ sboxes,
                                                   const u32* __restrict__ kcount,
                                                   u64* __restrict__ mask,
                                                   unsigned char* __restrict__ rownz) {
  const int i = blockIdx.x;       // sorted row
  const int b = blockIdx.y;
  const int K = (int)kcount[b];
  if (i >= K) return;
  const int wave = threadIdx.x >> 6;
  const int lane = threadIdx.x & 63;
  __shared__ u32 anyf[4];
  const float4* sb = sboxes + (size_t)b * NB;
  const float4 bi = sb[i];
  const float area_i = (bi.z - bi.x) * (bi.w - bi.y);
  u64* mrow = mask + ((size_t)b * NB + i) * WPR;
  bool any = false;
  for (int pass = 0; pass < WPR / 4; ++pass) {
    int w = pass * 4 + wave;
    u64 word = 0;
    if ((w + 1) * 64 > i && w * 64 < K) {   // uniform per wave
      int j = w * 64 + lane;
      float4 bj = sb[j];
      float lx = fmaxf(bi.x, bj.x);
      float ly = fmaxf(bi.y, bj.y);
      float rx = fminf(bi.z, bj.z);
      float ry = fminf(bi.w, bj.w);
      float iw = fmaxf(rx - lx, 0.0f);
      float ih = fmaxf(ry - ly, 0.0f);
      float inter = iw * ih;
      float area_j = (bj.z - bj.x) * (bj.w - bj.y);
      float iou = inter / (area_i + area_j - inter);
      bool pred = (j > i) && (j < K) && (iou > 0.5f);
      word = __ballot(pred);
      any = any || (word != 0ull);
    }
    if (lane == 0) mrow[w] = word;
  }
  if (lane == 0) anyf[wave] = any ? 1u : 0u;
  __syncthreads();
  if (threadIdx.x == 0) {
    u32 a = anyf[0] | anyf[1] | anyf[2] | anyf[3];
    rownz[(size_t)b * NB + i] = (unsigned char)(a ? 1 : 0);
  }
}

// ---------------------------------------------------------------------------
// Kernel 5: chunked greedy scan — MULTI-WAVE (TLP) version.
// 8 waves / image. Wave 0 resolves the serial diagonal; waves 1-7 OR kept
// rows' full masks into per-wave private registers (lane l owns words l,
// l+64). Per chunk, each row-OR wave posts its accumulated word c+1 to an
// LDS slot; resolver merges slots at the next chunk. Diagonal+rownz for
// chunk c+1 are prefetched by wave 0 during chunk c's parallel phase.
// ---------------------------------------------------------------------------
#define SCAN_WAVES 8
#define ROWW (SCAN_WAVES - 1)      // 7 row-OR waves
#define MAXROWS 10                 // 10-bit window per wave covers 64 bits

__device__ inline u64 rdl64(u64 v, int lane) {
  u32 lo = (u32)__builtin_amdgcn_readlane((int)(u32)v, lane);
  u32 hi = (u32)__builtin_amdgcn_readlane((int)(u32)(v >> 32), lane);
  return ((u64)hi << 32) | lo;
}

__device__ inline u64 shflxor64(u64 v, int off) {
  u32 lo = (u32)v, hi = (u32)(v >> 32);
  lo = (u32)__shfl_xor((int)lo, off, 64);
  hi = (u32)__shfl_xor((int)hi, off, 64);
  return ((u64)hi << 32) | lo;
}

__global__ __launch_bounds__(512) void scan_kernel(const u64* __restrict__ mask,
                                                   const unsigned char* __restrict__ rownz,
                                                   const u32* __restrict__ kcount,
                                                   u64* __restrict__ remv) {
  __shared__ u64 s_remv[WPR];          // finalized per-chunk rc words (1 KB)
  __shared__ u64 s_slot[SCAN_WAVES];   // per-wave word-(c+1) contributions
  __shared__ u64 s_ku;
  const int b = blockIdx.x;
  const int tid = threadIdx.x;
  const int w = tid >> 6;              // wave id 0..7
  const int l = tid & 63;
  const int K = (int)kcount[b];
  const u64* mb = mask + (size_t)b * NB * WPR;
  const unsigned char* nzb = rownz + (size_t)b * NB;
  const int NC = min(WPR, (K + 63) >> 6);

  if (tid < SCAN_WAVES) s_slot[tid] = 0;

  // per-wave private remv accumulators: lane l owns words l and l+64
  u64 plo = 0, phi = 0;

  // resolver prefetch for chunk 0
  u64 dw = 0;
  unsigned char nz = 0;
  if (w == 0 && NC > 0) {
    dw = (l < K) ? mb[(size_t)l * WPR] : 0ull;   // rows >= K unwritten (poison) -> guard
    nz = nzb[l];
  }
  __syncthreads();

  for (int c = 0; c < NC; ++c) {
    if (w == 0) {
      // merge word c: tail-init | OR of the 8 slots (3-step shfl reduce)
      u64 val = s_slot[l & (SCAN_WAVES - 1)];
#pragma unroll
      for (int off = 1; off < SCAN_WAVES; off <<= 1) val |= shflxor64(val, off);
      int lo = c * 64;
      u64 tail = (lo + 64 <= K) ? 0ull : ((~0ull) << (K - lo));   // lo < K since c < NC
      u64 rc = val | tail;
      u64 nzword = __ballot(nz != 0);
      // serial within-chunk resolve, pruned by current rc
      u64 nzd = __ballot(dw != 0ull) & ~rc;
      while (nzd) {
        int t = __builtin_ctzll(nzd);
        rc |= rdl64(dw, t);
        nzd &= ~(1ull << t) & ~rc;
      }
      u64 ku = (~rc) & nzword;
      if (l == 0) { s_remv[c] = rc; s_ku = ku; }
    }
    __syncthreads();                    // barrier A: rc/ku published

    u64 ku = s_ku;
    if (w == 0) {
      // prefetch next chunk's diagonal + rownz (latency hides under row-ORs)
      if (c + 1 < NC) {
        int i = (c + 1) * 64 + l;
        dw = (i < K) ? mb[(size_t)i * WPR + (c + 1)] : 0ull;
        nz = nzb[i];
      } else { dw = 0; nz = 0; }
    } else {
      // row-OR: wave w owns bit-window [(w-1)*10, (w-1)*10+10) of ku
      u64 kk = (ku >> ((w - 1) * MAXROWS));
      if ((w - 1) * MAXROWS + MAXROWS < 64)
        kk &= (1ull << MAXROWS) - 1ull;
      if (kk) {
        int base = c * 64 + (w - 1) * MAXROWS;
        u64 lo_[MAXROWS], hi_[MAXROWS];
#pragma unroll
        for (int q = 0; q < MAXROWS; ++q) {
          lo_[q] = 0; hi_[q] = 0;
          bool has = (kk != 0ull);
          int t = has ? __builtin_ctzll(kk) : 0;
          if (has) kk &= kk - 1;
          if (has) {
            const u64* rp = mb + (size_t)(base + t) * WPR;
            lo_[q] = rp[l];
            hi_[q] = rp[64 + l];
          }
        }
#pragma unroll
        for (int q = 0; q < MAXROWS; ++q) { plo |= lo_[q]; phi |= hi_[q]; }
      }
    }
    // post accumulated word c+1 to this wave's slot
    if (w > 0 && c + 1 < NC) {
      int wsel = c + 1;
      u64 v = (wsel < 64) ? plo : phi;
      if (l == (wsel & 63)) s_slot[w] = v;
    }
    __syncthreads();                    // barrier B: slots/privs settled
  }

  // write out remv: finalized words from LDS; words >= NC are all-suppressed
  for (int t = tid; t < WPR; t += 512) {
    remv[(size_t)b * WPR + t] = (t < NC) ? s_remv[t] : ~0ull;
  }
}

// ---------------------------------------------------------------------------
// Kernel 6: output write
// ---------------------------------------------------------------------------
__global__ void output_kernel(const float4* __restrict__ sboxes,
                              const float* __restrict__ sprob,
                              const u64* __restrict__ remv,
                              const u32* __restrict__ kcount,
                              float* __restrict__ out) {
  int idx = blockIdx.x * blockDim.x + threadIdx.x;
  if (idx >= BIMG * NB) return;
  int b = idx / NB;
  int p = idx - b * NB;
  int K = (int)kcount[b];
  u64 w = remv[(size_t)b * WPR + (p >> 6)];
  bool kp = (p < K) && !((w >> (p & 63)) & 1ull);
  float4 bv = sboxes[idx];
  if (!kp) { bv.x = 0.0f; bv.y = 0.0f; bv.z = 0.0f; bv.w = 0.0f; }
  ((float4*)out)[idx] = bv;
  out[(size_t)BIMG * NB * 4 + idx] = kp ? sprob[idx] : 0.0f;
  out[(size_t)BIMG * NB * 5 + idx] = kp ? 1.0f : 0.0f;
}

// ---------------------------------------------------------------------------
// Fallback NMS kernel (used only if workspace is too small)
// ---------------------------------------------------------------------------
__global__ __launch_bounds__(1024) void nms_kernel(const u64* __restrict__ keys,
                                                   const float4* __restrict__ boxes,
                                                   const float* __restrict__ prob,
                                                   const u32* __restrict__ kcount,
                                                   float* __restrict__ out) {
  __shared__ float4 sb[NB];
  __shared__ unsigned char flag[NB];
  const int b = blockIdx.x;
  const int t = threadIdx.x;
  const u64* kb = keys + (size_t)b * NB;
  const float4* bx = boxes + (size_t)b * NB;
  const int K = (int)kcount[b];

  for (int p = t; p < NB; p += 1024) {
    u32 idx = (u32)(~kb[p]);
    sb[p] = bx[idx];
    flag[p] = (p < K) ? (unsigned char)0 : (unsigned char)1;
  }
  __syncthreads();

  for (int i = 0; i < K; ++i) {
    if (flag[i]) continue;
    float4 bi = sb[i];
    float area_i = (bi.z - bi.x) * (bi.w - bi.y);
    for (int j = i + 1 + t; j < K; j += 1024) {
      float4 bj = sb[j];
      float lx = fmaxf(bi.x, bj.x);
      float ly = fmaxf(bi.y, bj.y);
      float rx = fminf(bi.z, bj.z);
      float ry = fminf(bi.w, bj.w);
      float iw = fmaxf(rx - lx, 0.0f);
      float ih = fmaxf(ry - ly, 0.0f);
      float inter = iw * ih;
      float area_j = (bj.z - bj.x) * (bj.w - bj.y);
      float iou = inter / (area_i + area_j - inter);
      if (iou > 0.5f) flag[j] = (unsigned char)1;
    }
    __syncthreads();
  }

  float4* oboxes = (float4*)(out) + (size_t)b * NB;
  float* oscores = out + (size_t)BIMG * NB * 4 + (size_t)b * NB;
  float* okeep   = out + (size_t)BIMG * NB * 5 + (size_t)b * NB;
  const float* pb = prob + (size_t)b * NB;
  for (int p = t; p < NB; p += 1024) {
    bool kp = (p < K) && (flag[p] == 0);
    float4 bv = sb[p];
    if (!kp) { bv.x = 0.0f; bv.y = 0.0f; bv.z = 0.0f; bv.w = 0.0f; }
    oboxes[p] = bv;
    u32 idx = (u32)(~kb[p]);
    oscores[p] = kp ? pb[idx] : 0.0f;
    okeep[p] = kp ? 1.0f : 0.0f;
  }
}

// ---------------------------------------------------------------------------
extern "C" void kernel_launch(void* const* d_in, const int* in_sizes, int n_in,
                              void* d_out, int out_size, void* d_ws, size_t ws_size,
                              hipStream_t stream) {
  const float* offsets = (const float*)d_in[0];   // [B,N,4] f32
  const float* labels  = (const float*)d_in[1];   // [B,N,1] f32
  const float* anchors = (const float*)d_in[2];   // [N,4]   f32
  float* out = (float*)d_out;

  char* ws = (char*)d_ws;
  u32*    kcount = (u32*)(ws + WS_KCOUNT);
  u64*    keys   = (u64*)(ws + WS_KEYS);
  float4* boxes  = (float4*)(ws + WS_BOXES);
  float*  prob   = (float*)(ws + WS_PROB);
  float4* sboxes = (float4*)(ws + WS_SBOXES);
  float*  sprob  = (float*)(ws + WS_SPROB);

  int total = BIMG * NB;
  decode_kernel<<<(total + 255) / 256, 256, 0, stream>>>(
      offsets, labels, anchors, keys, boxes, prob);

  sort_kernel<<<BIMG, 1024, 0, stream>>>(keys, boxes, prob, sboxes, sprob, kcount);

  if (ws_size >= WS_NEEDED) {
    u64*    remv   = (u64*)(ws + WS_REMV);
    u64*    mask   = (u64*)(ws + WS_MASK);
    unsigned char* rownz = (unsigned char*)(ws + WS_ROWNZ);

    mask_kernel<<<dim3(NB, BIMG), 256, 0, stream>>>(sboxes, kcount, mask, rownz);

    scan_kernel<<<BIMG, 512, 0, stream>>>(mask, rownz, kcount, remv);

    output_kernel<<<(total + 255) / 256, 256, 0, stream>>>(
        sboxes, sprob, remv, kcount, out);
  } else {
    nms_kernel<<<BIMG, 1024, 0, stream>>>(keys, boxes, prob, kcount, out);
  }
}